// Round 12
// baseline (4223.586 us; speedup 1.0000x reference)
//
#include <hip/hip_runtime.h>
#include <cstdint>
#include <cstddef>

// Problem constants (match reference)
#define NIT    500
#define GAMMA_ 5.0f
#define CC_    1e-3f
#define KAPPA_ 2.0627128075074256f
#define PEN_   100.0f
#define LR_    0.01f

// d_ws layout: pbuf [128 b][2 dir][2 parity][100] f32 = 204800 B, then flags [256] int
#define PBUF_BYTES (128*2*2*100*4)
#define FLAG_COUNT 256

// Cross-WG primitives (r11-proven): system-scope RELAXED RMWs execute at the
// coherence point -> no stale L2 reads AND no cache-wide maintenance ops
// (agent-scope acquire/release emitted per-iter L2 wb/inv = the 6us/iter floor
// r1-r10 sat on). Ordering: VMFENCE between data RMWs and flag RMW.
#define VMFENCE() asm volatile("s_waitcnt vmcnt(0)" ::: "memory")
__device__ __forceinline__ float sysLoadF(float* p) {
  return __hip_atomic_fetch_add(p, 0.0f, __ATOMIC_RELAXED, __HIP_MEMORY_SCOPE_SYSTEM);
}
__device__ __forceinline__ void sysStoreF(float* p, float v) {
  (void)__hip_atomic_exchange(p, v, __ATOMIC_RELAXED, __HIP_MEMORY_SCOPE_SYSTEM);
}
__device__ __forceinline__ int sysLoadI(int* p) {
  return __hip_atomic_fetch_add(p, 0, __ATOMIC_RELAXED, __HIP_MEMORY_SCOPE_SYSTEM);
}
__device__ __forceinline__ void sysStoreI(int* p, int v) {
  (void)__hip_atomic_exchange(p, v, __ATOMIC_RELAXED, __HIP_MEMORY_SCOPE_SYSTEM);
}
// Intra-WG flags live in LDS: workgroup-scope acquire/release is cheap
// (lgkmcnt waits only, no cache ops).
__device__ __forceinline__ int ldsLoadAcq(int* p) {
  return __hip_atomic_load(p, __ATOMIC_ACQUIRE, __HIP_MEMORY_SCOPE_WORKGROUP);
}
__device__ __forceinline__ void ldsStoreRel(int* p, int v) {
  __hip_atomic_store(p, v, __ATOMIC_RELEASE, __HIP_MEMORY_SCOPE_WORKGROUP);
}

__device__ __forceinline__ float rdlane(float v, int lane) {
  return __int_as_float(__builtin_amdgcn_readlane(__float_as_int(v), lane));
}

// Wave64 sum via DPP, total broadcast from lane 63. Verified r5..r11.
__device__ __forceinline__ float wred64(float x) {
  int t;
  t = __builtin_amdgcn_update_dpp(0, __float_as_int(x), 0x111, 0xf, 0xf, true); x += __int_as_float(t);
  t = __builtin_amdgcn_update_dpp(0, __float_as_int(x), 0x112, 0xf, 0xf, true); x += __int_as_float(t);
  t = __builtin_amdgcn_update_dpp(0, __float_as_int(x), 0x114, 0xf, 0xf, true); x += __int_as_float(t);
  t = __builtin_amdgcn_update_dpp(0, __float_as_int(x), 0x118, 0xf, 0xf, true); x += __int_as_float(t);
  t = __builtin_amdgcn_update_dpp(0, __float_as_int(x), 0x142, 0xa, 0xf, true); x += __int_as_float(t);
  t = __builtin_amdgcn_update_dpp(0, __float_as_int(x), 0x143, 0xc, 0xf, true); x += __int_as_float(t);
  return rdlane(x, 63);
}

// 256 WGs, one per (b,half): 6 heads x 2 waves. NO WG barrier in the loop:
// heads free-run (skew<=1 via exact-k wf gating) so head j's post overlaps
// head j's and j''s matvecs across the 12 waves. r7 proved this architecture
// correct; it was re-convoyed then by the agent-scope boundary floor that r11
// removed. S constant-indexed (AGPR-resident; r9: runtime index -> 19.6GB spill).
__global__ __launch_bounds__(768, 1) void mpo_solver(
    const float* __restrict__ mu, const float* __restrict__ L,
    const float* __restrict__ wprev, const float* __restrict__ climit,
    float* __restrict__ out, float* __restrict__ pbuf, int* __restrict__ flags)
{
  const int tid  = threadIdx.x;
  const int lane = tid & 63;
  const int wave = __builtin_amdgcn_readfirstlane(tid >> 6);  // 0..11
  const int j    = wave >> 1;       // head 0..5
  const int sec  = wave & 1;        // 0 = rows 0-49 + post ("A"), 1 = rows 50-99 ("B")
  const int bid  = blockIdx.x;
  const int b    = bid & 127;
  const int half = bid >> 7;        // 0: heads 0-5, 1: heads 6-11
  const int h    = half * 6 + j;
  const int bh   = b * 12 + h;

  __shared__ float wbuf[2][6][100];   // ring-2 iterate per head (slot k&1 = w(k))
  __shared__ float ybuf[6][100];      // y rows 50-99 per head (B's half; single-buffer safe)
  __shared__ int   yf[6];             // B published y-upper of iter k -> k+1
  __shared__ int   wf[6];             // A published w(k+1) in wbuf[(k+1)&1] -> k+1

  const float* Lb = L + (size_t)bh * 10000;

  // ---------- Phase 0: SYRK. Lane owns row r of S = L L^T (fp32 regs/AGPRs). ----------
  float S[100];
#pragma unroll
  for (int c = 0; c < 100; ++c) S[c] = 0.f;
  const int r = sec * 50 + lane;      // valid row iff lane < 50
  if (lane < 50) {
#pragma unroll 1
    for (int mc = 0; mc < 25; ++mc) {
      float4 lr = *(const float4*)(Lb + r * 100 + mc * 4);
#pragma unroll
      for (int c = 0; c < 100; ++c) {
        const float* Lc = Lb + c * 100 + mc * 4;   // wave-uniform -> scalar loads
        S[c] = fmaf(lr.x, Lc[0], fmaf(lr.y, Lc[1], fmaf(lr.z, Lc[2], fmaf(lr.w, Lc[3], S[c]))));
      }
    }
  }

  const bool val1 = (lane < 36);
  float mu0 = mu[(size_t)bh * 100 + lane];
  float mu1 = val1 ? mu[(size_t)bh * 100 + 64 + lane] : 0.f;
  float wp0 = wprev[b * 100 + lane];
  float wp1 = val1 ? wprev[b * 100 + 64 + lane] : 0.f;
  float lim = climit[b];

  if (sec == 0) {
    wbuf[0][j][lane] = wp0;
    if (val1) wbuf[0][j][64 + lane] = wp1;
  }
  if (tid < 6) { wf[tid] = 0; yf[tid] = 0; }
  __syncthreads();   // only barrier: initial state + flags

  const bool hasNext = (h < 11);
  const bool isPubL  = (half == 0) && (j == 5);  // publishes head 5, consumes head 6
  const bool isPubH  = (half == 1) && (j == 0);  // publishes head 6, consumes head 5
  const int  flagPub = isPubL ? (b * 2 + 0) : (b * 2 + 1);
  const int  flagCon = isPubL ? (b * 2 + 1) : (b * 2 + 0);
  bool dead = false;

  if (sec == 1) {
    // ---------------- B wave: upper-half matvec only ----------------
    for (int k = 0; k < NIT; ++k) {
      if (!dead && ldsLoadAcq(&wf[j]) < k) {
        long g = 0;
        while (ldsLoadAcq(&wf[j]) < k) {
          __builtin_amdgcn_s_sleep(1);
          if (++g > (1L << 18)) { dead = true; break; }
        }
      }
      float a0 = 0.f, a1 = 0.f, a2 = 0.f, a3 = 0.f;
      const float* wrow = wbuf[k & 1][j];
#pragma unroll
      for (int q = 0; q < 25; ++q) {
        float4 wq = *(const float4*)(wrow + q * 4);
        a0 = fmaf(wq.x, S[q * 4 + 0], a0);
        a1 = fmaf(wq.y, S[q * 4 + 1], a1);
        a2 = fmaf(wq.z, S[q * 4 + 2], a2);
        a3 = fmaf(wq.w, S[q * 4 + 3], a3);
      }
      if (lane < 50) ybuf[j][50 + lane] = (a0 + a2) + (a1 + a3);
      if (lane == 0) ldsStoreRel(&yf[j], k + 1);
    }
  } else {
    // ---------------- A wave: lower-half matvec + post ----------------
    float w0 = wp0, w1 = wp1;         // iterate in registers (also mirrored in wbuf)
    float thp = -3.0e38f;             // warm Michelot seed
    for (int k = 0; k < NIT; ++k) {
      const int p = k & 1;

      // matvec lower half; w(k) is in wbuf[p][j] (this wave wrote it — no wait)
      float yloc;
      {
        float a0 = 0.f, a1 = 0.f, a2 = 0.f, a3 = 0.f;
        const float* wrow = wbuf[p][j];
#pragma unroll
        for (int q = 0; q < 25; ++q) {
          float4 wq = *(const float4*)(wrow + q * 4);
          a0 = fmaf(wq.x, S[q * 4 + 0], a0);
          a1 = fmaf(wq.y, S[q * 4 + 1], a1);
          a2 = fmaf(wq.z, S[q * 4 + 2], a2);
          a3 = fmaf(wq.w, S[q * 4 + 3], a3);
        }
        yloc = (a0 + a2) + (a1 + a3);
      }

      // cross-WG prefetch (non-blocking) right after matvec
      float pf0 = 0.f, pf1 = 0.f;
      bool pfReady = false;
      if ((isPubL || isPubH) && k > 0) {
        if (sysLoadI(&flags[flagCon]) >= k) {
          float* src = pbuf + ((size_t)flagCon * 2 + (k & 1)) * 100;
          pf0 = sysLoadF(&src[lane]);
          pf1 = val1 ? sysLoadF(&src[64 + lane]) : 0.f;
          pfReady = true;
        }
      }

      // neighbor w(k) (exact k; intra-WG gated by wf, cross-WG by global flag)
      float wl0, wl1, wn0 = 0.f, wn1 = 0.f;
      if (j == 0) {
        if (half == 0 || k == 0) { wl0 = wp0; wl1 = wp1; }
        else {
          if (!pfReady) {
            if (!dead && sysLoadI(&flags[flagCon]) < k) {
              long g = 0;
              while (sysLoadI(&flags[flagCon]) < k) {
                __builtin_amdgcn_s_sleep(2);
                if (++g > (1L << 17)) { dead = true; break; }
              }
            }
            float* src = pbuf + ((size_t)flagCon * 2 + (k & 1)) * 100;
            pf0 = sysLoadF(&src[lane]);
            pf1 = val1 ? sysLoadF(&src[64 + lane]) : 0.f;
          }
          wl0 = pf0; wl1 = pf1;
        }
      } else {
        if (!dead && ldsLoadAcq(&wf[j - 1]) < k) {
          long g = 0;
          while (ldsLoadAcq(&wf[j - 1]) < k) {
            __builtin_amdgcn_s_sleep(1);
            if (++g > (1L << 18)) { dead = true; break; }
          }
        }
        wl0 = wbuf[p][j - 1][lane];
        wl1 = val1 ? wbuf[p][j - 1][64 + lane] : 0.f;
      }
      if (hasNext) {
        if (j == 5) {   // half==0 boundary: next is head 6 (cross-WG)
          if (k == 0) { wn0 = wp0; wn1 = wp1; }
          else {
            if (!pfReady) {
              if (!dead && sysLoadI(&flags[flagCon]) < k) {
                long g = 0;
                while (sysLoadI(&flags[flagCon]) < k) {
                  __builtin_amdgcn_s_sleep(2);
                  if (++g > (1L << 17)) { dead = true; break; }
                }
              }
              float* src = pbuf + ((size_t)flagCon * 2 + (k & 1)) * 100;
              pf0 = sysLoadF(&src[lane]);
              pf1 = val1 ? sysLoadF(&src[64 + lane]) : 0.f;
            }
            wn0 = pf0; wn1 = pf1;
          }
        } else {
          if (!dead && ldsLoadAcq(&wf[j + 1]) < k) {
            long g = 0;
            while (ldsLoadAcq(&wf[j + 1]) < k) {
              __builtin_amdgcn_s_sleep(1);
              if (++g > (1L << 18)) { dead = true; break; }
            }
          }
          wn0 = wbuf[p][j + 1][lane];
          wn1 = val1 ? wbuf[p][j + 1][64 + lane] : 0.f;
        }
      }

      // partner y-half
      if (!dead && ldsLoadAcq(&yf[j]) < k + 1) {
        long g = 0;
        while (ldsLoadAcq(&yf[j]) < k + 1) {
          __builtin_amdgcn_s_sleep(1);
          if (++g > (1L << 18)) { dead = true; break; }
        }
      }
      float y0 = (lane < 50) ? yloc : ybuf[j][lane];
      float y1 = val1 ? ybuf[j][64 + lane] : 0.f;

      float ret = wred64(fmaf(mu0, w0, mu1 * w1));
      float s2  = wred64(fmaf(y0, w0, y1 * w1));
      float sigma = sqrtf(s2 + 1e-12f);
      float z     = KAPPA_ * sigma - ret - lim;
      float act   = (z > 0.f) ? 1.f : 0.f;
      float cY    = 2.f * GAMMA_ + act * (PEN_ * KAPPA_ / sigma);
      float cM    = -(1.f + act * PEN_);

      float dw0 = w0 - wl0;
      float g0  = fmaf(cM, mu0, cY * y0) + CC_ * (dw0 * rsqrtf(fmaf(dw0, dw0, 1e-10f)));
      if (hasNext) { float dn0 = wn0 - w0; g0 -= CC_ * (dn0 * rsqrtf(fmaf(dn0, dn0, 1e-10f))); }
      float v0 = fmaf(-LR_, g0, w0);
      float v1 = 0.f;
      if (val1) {
        float dw1 = w1 - wl1;
        float g1  = fmaf(cM, mu1, cY * y1) + CC_ * (dw1 * rsqrtf(fmaf(dw1, dw1, 1e-10f)));
        if (hasNext) { float dn1 = wn1 - w1; g1 -= CC_ * (dn1 * rsqrtf(fmaf(dn1, dn1, 1e-10f))); }
        v1 = fmaf(-LR_, g1, w1);
      }

      // ---- Michelot projection, warm-started (r8/r10/r11-verified numerics) ----
      float a1m = val1 ? 1.f : 0.f;
      float na0 = (v0 > thp) ? 1.f : 0.f;
      float na1 = (val1 && (v1 > thp)) ? 1.f : 0.f;
      float Ssum = wred64(na0 * v0 + na1 * v1);
      float Cnt  = wred64(na0 + na1);
      if (Cnt < 0.5f) { Ssum = wred64(v0 + a1m * v1); Cnt = 100.f; }
      float theta = (Ssum - 1.f) / Cnt;
      for (int it = 0; it < 112; ++it) {
        na0 = (v0 > theta) ? 1.f : 0.f;
        na1 = (val1 && (v1 > theta)) ? 1.f : 0.f;
        float ns = wred64(na0 * v0 + na1 * v1);
        float nc = wred64(na0 + na1);
        if (nc == Cnt && ns == Ssum) break;
        if (it == 7) {  // warm-start may cycle: reset to full support (monotone)
          ns = wred64(v0 + a1m * v1);
          nc = 100.f;
        }
        Ssum = ns; Cnt = nc;
        theta = (Ssum - 1.f) / Cnt;
      }
      thp = theta;
      w0 = fmaxf(v0 - theta, 0.f);
      w1 = val1 ? fmaxf(v1 - theta, 0.f) : 0.f;

      // publish w(k+1): ring-2 safe — wf[j±1]>=k (observed above) implies the
      // neighbors consumed w(k-1); yf>=k+1 implies B consumed w(k).
      wbuf[1 - p][j][lane] = w0;
      if (val1) wbuf[1 - p][j][64 + lane] = w1;
      if (lane == 0) ldsStoreRel(&wf[j], k + 1);

      if (isPubL || isPubH) {
        float* dst = pbuf + ((size_t)flagPub * 2 + ((k + 1) & 1)) * 100;
        sysStoreF(&dst[lane], w0);
        if (val1) sysStoreF(&dst[64 + lane], w1);
        if (lane == 0) {
          VMFENCE();   // data RMWs at coherence point before flag RMW issues
          sysStoreI(&flags[flagPub], k + 1);
        }
      }
    }

    float* o = out + (size_t)bh * 100;
    o[lane] = w0;
    if (val1) o[64 + lane] = w1;
  }
}

extern "C" void kernel_launch(void* const* d_in, const int* in_sizes, int n_in,
                              void* d_out, int out_size, void* d_ws, size_t ws_size,
                              hipStream_t stream) {
  const float* mu = (const float*)d_in[0];
  const float* L  = (const float*)d_in[1];
  const float* wp = (const float*)d_in[2];
  const float* cl = (const float*)d_in[3];
  float* pbuf  = (float*)d_ws;
  int*   flags = (int*)((char*)d_ws + PBUF_BYTES);
  hipMemsetAsync(flags, 0, FLAG_COUNT * sizeof(int), stream);
  hipLaunchKernelGGL(mpo_solver, dim3(256), dim3(768), 0, stream,
                     mu, L, wp, cl, (float*)d_out, pbuf, flags);
}

// Round 13
// 1837.120 us; speedup vs baseline: 2.2990x; 2.2990x over previous
//
#include <hip/hip_runtime.h>
#include <cstdint>
#include <cstddef>

// Problem constants (match reference)
#define NIT    500
#define GAMMA_ 5.0f
#define CC_    1e-3f
#define KAPPA_ 2.0627128075074256f
#define PEN_   100.0f
#define LR_    0.01f

// d_ws layout: pbuf [128 b][2 dir][2 parity][100] f32 = 204800 B, then flags [256] int
#define PBUF_BYTES (128*2*2*100*4)
#define FLAG_COUNT 256

// Cross-WG primitives v3 (r11/r12 lessons):
//  - relaxed SYSTEM-scope atomic LOAD/STORE: lowers to global_load/store with
//    sc0/sc1 (bypass L0/L2 to the coherence point). No stale reads, no cache-wide
//    maintenance (r11's win), and — unlike r11's RMWs — no write-allocation or
//    same-address serialization (r12's regression: RMW polls = HBM atomic storm).
//  - VMFENCE orders data stores before the flag store (producer side only).
#define VMFENCE() asm volatile("s_waitcnt vmcnt(0)" ::: "memory")
__device__ __forceinline__ float sysLoadF(float* p) {
  return __hip_atomic_load(p, __ATOMIC_RELAXED, __HIP_MEMORY_SCOPE_SYSTEM);
}
__device__ __forceinline__ void sysStoreF(float* p, float v) {
  __hip_atomic_store(p, v, __ATOMIC_RELAXED, __HIP_MEMORY_SCOPE_SYSTEM);
}
__device__ __forceinline__ int sysLoadI(int* p) {
  return __hip_atomic_load(p, __ATOMIC_RELAXED, __HIP_MEMORY_SCOPE_SYSTEM);
}
__device__ __forceinline__ void sysStoreI(int* p, int v) {
  __hip_atomic_store(p, v, __ATOMIC_RELAXED, __HIP_MEMORY_SCOPE_SYSTEM);
}
// Flag poll: ONE coherence-point load per wave (lane 0), broadcast in-register.
__device__ __forceinline__ int flagRead(int* p, int lane) {
  int f = 0;
  if (lane == 0) f = sysLoadI(p);
  return __builtin_amdgcn_readfirstlane(f);
}

__device__ __forceinline__ float rdlane(float v, int lane) {
  return __int_as_float(__builtin_amdgcn_readlane(__float_as_int(v), lane));
}

// Wave64 sum via DPP, total broadcast from lane 63. Verified r5..r12.
__device__ __forceinline__ float wred64(float x) {
  int t;
  t = __builtin_amdgcn_update_dpp(0, __float_as_int(x), 0x111, 0xf, 0xf, true); x += __int_as_float(t);
  t = __builtin_amdgcn_update_dpp(0, __float_as_int(x), 0x112, 0xf, 0xf, true); x += __int_as_float(t);
  t = __builtin_amdgcn_update_dpp(0, __float_as_int(x), 0x114, 0xf, 0xf, true); x += __int_as_float(t);
  t = __builtin_amdgcn_update_dpp(0, __float_as_int(x), 0x118, 0xf, 0xf, true); x += __int_as_float(t);
  t = __builtin_amdgcn_update_dpp(0, __float_as_int(x), 0x142, 0xa, 0xf, true); x += __int_as_float(t);
  t = __builtin_amdgcn_update_dpp(0, __float_as_int(x), 0x143, 0xc, 0xf, true); x += __int_as_float(t);
  return rdlane(x, 63);
}

// r11 skeleton verbatim (256 WGs, (b,half), 6 heads x 2 waves, 2 barriers/iter —
// r12 proved barrier-free free-running regresses via poll multiplication).
// Changes vs r11: load/store primitives (above), lane0 flag polls, and DEFERRED
// flag publish (VMFENCE+flag flushed after next matvec, off the barrier convoy).
// S constant-indexed only (r9: runtime index -> scratch spill -> 19.6 GB FETCH).
__global__ __launch_bounds__(768, 1) void mpo_solver(
    const float* __restrict__ mu, const float* __restrict__ L,
    const float* __restrict__ wprev, const float* __restrict__ climit,
    float* __restrict__ out, float* __restrict__ pbuf, int* __restrict__ flags)
{
  const int tid  = threadIdx.x;
  const int lane = tid & 63;
  const int wave = __builtin_amdgcn_readfirstlane(tid >> 6);  // 0..11
  const int j    = wave >> 1;       // local head 0..5
  const int sec  = wave & 1;        // 0 = rows 0-49 + post, 1 = rows 50-99
  const int bid  = blockIdx.x;
  const int b    = bid & 127;
  const int half = bid >> 7;        // 0: heads 0-5, 1: heads 6-11
  const int h    = half * 6 + j;    // global head
  const int bh   = b * 12 + h;

  __shared__ float wbuf[2][6][100];   // double-buffered w per head
  __shared__ float ybuf[6][100];      // y rows 50-99 per head (B-wave's half)

  const float* Lb = L + (size_t)bh * 10000;

  // ---------- Phase 0: SYRK. Lane owns row r of S = L L^T (fp32 regs/AGPRs). ----------
  float S[100];
#pragma unroll
  for (int c = 0; c < 100; ++c) S[c] = 0.f;
  const int r = sec * 50 + lane;      // valid row iff lane < 50
  if (lane < 50) {
#pragma unroll 1
    for (int mc = 0; mc < 25; ++mc) {
      float4 lr = *(const float4*)(Lb + r * 100 + mc * 4);
#pragma unroll
      for (int c = 0; c < 100; ++c) {
        const float* Lc = Lb + c * 100 + mc * 4;   // wave-uniform -> scalar loads
        S[c] = fmaf(lr.x, Lc[0], fmaf(lr.y, Lc[1], fmaf(lr.z, Lc[2], fmaf(lr.w, Lc[3], S[c]))));
      }
    }
  }

  const bool val1 = (lane < 36);
  float mu0 = mu[(size_t)bh * 100 + lane];
  float mu1 = val1 ? mu[(size_t)bh * 100 + 64 + lane] : 0.f;
  float wp0 = wprev[b * 100 + lane];
  float wp1 = val1 ? wprev[b * 100 + 64 + lane] : 0.f;
  float lim = climit[b];

  float w0 = wp0, w1 = wp1;           // post wave's iterate (n = lane, 64+lane)

  if (sec == 0) {
    wbuf[0][j][lane] = wp0;
    if (val1) wbuf[0][j][64 + lane] = wp1;
  }
  __syncthreads();

  const bool hasNext = (h < 11);
  const bool isPubL  = (half == 0) && (j == 5);  // publishes head 5, consumes head 6
  const bool isPubH  = (half == 1) && (j == 0);  // publishes head 6, consumes head 5
  const int  flagPub = isPubL ? (b * 2 + 0) : (b * 2 + 1);
  const int  flagCon = isPubL ? (b * 2 + 1) : (b * 2 + 0);
  const bool isCon   = (sec == 0) && (isPubL || isPubH);
  bool dead = false;
  int  pendFlag = 0;                  // deferred cross-WG flag value
  float thp = -3.0e38f;               // warm Michelot seed; k=0 -> full support

  for (int k = 0; k < NIT; ++k) {
    const int p = k & 1;

    // ---------- matvec y = S * w_k: wave-uniform ds_read_b128 broadcast ----------
    float yloc;
    {
      float a0 = 0.f, a1 = 0.f, a2 = 0.f, a3 = 0.f;
      const float* wrow = wbuf[p][j];
#pragma unroll
      for (int q = 0; q < 25; ++q) {
        float4 wq = *(const float4*)(wrow + q * 4);
        a0 = fmaf(wq.x, S[q * 4 + 0], a0);
        a1 = fmaf(wq.y, S[q * 4 + 1], a1);
        a2 = fmaf(wq.z, S[q * 4 + 2], a2);
        a3 = fmaf(wq.w, S[q * 4 + 3], a3);
      }
      yloc = (a0 + a2) + (a1 + a3);
      if (sec == 1 && lane < 50) ybuf[j][50 + lane] = yloc;  // only B publishes its half
    }

    // ---------- flush deferred flag: data stores drained during matvec ----------
    if (isCon && pendFlag) {
      VMFENCE();                      // cheap: publish stores retired ~400 cyc ago
      if (lane == 0) sysStoreI(&flags[flagPub], pendFlag);
      pendFlag = 0;
    }

    // ---------- boundary prefetch AFTER matvec ----------
    float pf0 = 0.f, pf1 = 0.f;
    bool pfReady = false;
    if (isCon && k > 0) {
      if (flagRead(&flags[flagCon], lane) >= k) {
        float* src = pbuf + ((size_t)flagCon * 2 + (k & 1)) * 100;
        pf0 = sysLoadF(&src[lane]);
        pf1 = val1 ? sysLoadF(&src[64 + lane]) : 0.f;
        pfReady = true;
      }
    }
    __syncthreads();

    // ---------- post phase: primary wave per head ----------
    if (sec == 0) {
      // y[lane]: rows 0-49 are THIS wave's registers; rows 50-99 from B via ybuf
      float y0 = (lane < 50) ? yloc : ybuf[j][lane];
      float y1 = val1 ? ybuf[j][64 + lane] : 0.f;

      float ret = wred64(fmaf(mu0, w0, mu1 * w1));
      float s2  = wred64(fmaf(y0, w0, y1 * w1));
      float sigma = sqrtf(s2 + 1e-12f);
      float z     = KAPPA_ * sigma - ret - lim;
      float act   = (z > 0.f) ? 1.f : 0.f;
      float cY    = 2.f * GAMMA_ + act * (PEN_ * KAPPA_ / sigma);
      float cM    = -(1.f + act * PEN_);

      // neighbor w (iterate k exactly — Jacobi, matches reference)
      float wl0, wl1, wn0 = 0.f, wn1 = 0.f;
      if (j == 0) {
        if (half == 0 || k == 0) { wl0 = wp0; wl1 = wp1; }
        else {
          if (!pfReady) {
            if (!dead) {
              long guard = 0;
              while (flagRead(&flags[flagCon], lane) < k) {
                __builtin_amdgcn_s_sleep(2);
                if (++guard > (1L << 17)) { dead = true; break; }
              }
            }
            float* src = pbuf + ((size_t)flagCon * 2 + (k & 1)) * 100;
            pf0 = sysLoadF(&src[lane]);
            pf1 = val1 ? sysLoadF(&src[64 + lane]) : 0.f;
          }
          wl0 = pf0; wl1 = pf1;
        }
      } else { wl0 = wbuf[p][j - 1][lane]; wl1 = val1 ? wbuf[p][j - 1][64 + lane] : 0.f; }
      if (hasNext) {
        if (j == 5) {  // half==0 boundary: next is head 6
          if (k == 0) { wn0 = wp0; wn1 = wp1; }
          else {
            if (!pfReady) {
              if (!dead) {
                long guard = 0;
                while (flagRead(&flags[flagCon], lane) < k) {
                  __builtin_amdgcn_s_sleep(2);
                  if (++guard > (1L << 17)) { dead = true; break; }
                }
              }
              float* src = pbuf + ((size_t)flagCon * 2 + (k & 1)) * 100;
              pf0 = sysLoadF(&src[lane]);
              pf1 = val1 ? sysLoadF(&src[64 + lane]) : 0.f;
            }
            wn0 = pf0; wn1 = pf1;
          }
        } else { wn0 = wbuf[p][j + 1][lane]; wn1 = val1 ? wbuf[p][j + 1][64 + lane] : 0.f; }
      }

      float dw0 = w0 - wl0;
      float g0  = fmaf(cM, mu0, cY * y0) + CC_ * (dw0 * rsqrtf(fmaf(dw0, dw0, 1e-10f)));
      if (hasNext) { float dn0 = wn0 - w0; g0 -= CC_ * (dn0 * rsqrtf(fmaf(dn0, dn0, 1e-10f))); }
      float v0 = fmaf(-LR_, g0, w0);
      float v1 = 0.f;
      if (val1) {
        float dw1 = w1 - wl1;
        float g1  = fmaf(cM, mu1, cY * y1) + CC_ * (dw1 * rsqrtf(fmaf(dw1, dw1, 1e-10f)));
        if (hasNext) { float dn1 = wn1 - w1; g1 -= CC_ * (dn1 * rsqrtf(fmaf(dn1, dn1, 1e-10f))); }
        v1 = fmaf(-LR_, g1, w1);
      }

      // ---- Michelot projection, warm-started (r8/r10/r11-verified numerics) ----
      float a1m = val1 ? 1.f : 0.f;
      float na0 = (v0 > thp) ? 1.f : 0.f;
      float na1 = (val1 && (v1 > thp)) ? 1.f : 0.f;
      float Ssum = wred64(na0 * v0 + na1 * v1);
      float Cnt  = wred64(na0 + na1);
      if (Cnt < 0.5f) { Ssum = wred64(v0 + a1m * v1); Cnt = 100.f; }
      float theta = (Ssum - 1.f) / Cnt;
      for (int it = 0; it < 112; ++it) {
        na0 = (v0 > theta) ? 1.f : 0.f;
        na1 = (val1 && (v1 > theta)) ? 1.f : 0.f;
        float ns = wred64(na0 * v0 + na1 * v1);
        float nc = wred64(na0 + na1);
        if (nc == Cnt && ns == Ssum) break;
        if (it == 7) {  // warm-start may cycle: reset to full support (monotone)
          ns = wred64(v0 + a1m * v1);
          nc = 100.f;
        }
        Ssum = ns; Cnt = nc;
        theta = (Ssum - 1.f) / Cnt;
      }
      thp = theta;
      w0 = fmaxf(v0 - theta, 0.f);
      w1 = val1 ? fmaxf(v1 - theta, 0.f) : 0.f;

      wbuf[1 - p][j][lane] = w0;
      if (val1) wbuf[1 - p][j][64 + lane] = w1;

      if (isPubL || isPubH) {
        float* dst = pbuf + ((size_t)flagPub * 2 + ((k + 1) & 1)) * 100;
        sysStoreF(&dst[lane], w0);
        if (val1) sysStoreF(&dst[64 + lane], w1);
        pendFlag = k + 1;             // flag flushed after next matvec (VMFENCE there)
      }
    }
    __syncthreads();
  }

  if (sec == 0) {
    float* o = out + (size_t)bh * 100;
    o[lane] = w0;
    if (val1) o[64 + lane] = w1;
  }
}

extern "C" void kernel_launch(void* const* d_in, const int* in_sizes, int n_in,
                              void* d_out, int out_size, void* d_ws, size_t ws_size,
                              hipStream_t stream) {
  const float* mu = (const float*)d_in[0];
  const float* L  = (const float*)d_in[1];
  const float* wp = (const float*)d_in[2];
  const float* cl = (const float*)d_in[3];
  float* pbuf  = (float*)d_ws;
  int*   flags = (int*)((char*)d_ws + PBUF_BYTES);
  hipMemsetAsync(flags, 0, FLAG_COUNT * sizeof(int), stream);
  hipLaunchKernelGGL(mpo_solver, dim3(256), dim3(768), 0, stream,
                     mu, L, wp, cl, (float*)d_out, pbuf, flags);
}

// Round 15
// 1686.679 us; speedup vs baseline: 2.5041x; 1.0892x over previous
//
#include <hip/hip_runtime.h>
#include <cstdint>
#include <cstddef>

// Problem constants (match reference)
#define NIT    500
#define GAMMA_ 5.0f
#define CC_    1e-3f
#define KAPPA_ 2.0627128075074256f
#define PEN_   100.0f
#define LR_    0.01f

// d_ws layout: pbuf [128 b][2 dir][2 parity][100] f32 = 204800 B, then flags [256] int.
// TOTAL ~206 KB. r6/r14 post-mortem: both 617 KB layouts failed with garbage-neighbor
// signatures while every <=410 KB layout passed -> treat ws budget as ~512 KB hard.
#define PBUF_BYTES (128*2*2*100*4)
#define FLAG_COUNT 256

// Cross-WG primitives (r11/r13-proven): relaxed SYSTEM-scope atomic load/store ->
// coherence point, no cache-wide maintenance (r11: agent acq/rel wb/inv was a
// ~6us/iter floor), no RMW serialization (r12: RMW polls = HBM atomic storm).
#define VMFENCE() asm volatile("s_waitcnt vmcnt(0)" ::: "memory")
__device__ __forceinline__ float sysLoadF(float* p) {
  return __hip_atomic_load(p, __ATOMIC_RELAXED, __HIP_MEMORY_SCOPE_SYSTEM);
}
__device__ __forceinline__ void sysStoreF(float* p, float v) {
  __hip_atomic_store(p, v, __ATOMIC_RELAXED, __HIP_MEMORY_SCOPE_SYSTEM);
}
__device__ __forceinline__ int sysLoadI(int* p) {
  return __hip_atomic_load(p, __ATOMIC_RELAXED, __HIP_MEMORY_SCOPE_SYSTEM);
}
__device__ __forceinline__ void sysStoreI(int* p, int v) {
  __hip_atomic_store(p, v, __ATOMIC_RELAXED, __HIP_MEMORY_SCOPE_SYSTEM);
}
__device__ __forceinline__ int flagRead(int* p, int lane) {
  int f = 0;
  if (lane == 0) f = sysLoadI(p);
  return __builtin_amdgcn_readfirstlane(f);
}
// Intra-WG flag in LDS: workgroup-scope acq/rel = lgkm waits only, no cache ops.
__device__ __forceinline__ int ldsLoadAcq(int* p) {
  return __hip_atomic_load(p, __ATOMIC_ACQUIRE, __HIP_MEMORY_SCOPE_WORKGROUP);
}
__device__ __forceinline__ void ldsStoreRel(int* p, int v) {
  __hip_atomic_store(p, v, __ATOMIC_RELEASE, __HIP_MEMORY_SCOPE_WORKGROUP);
}

__device__ __forceinline__ float rdlane(float v, int lane) {
  return __int_as_float(__builtin_amdgcn_readlane(__float_as_int(v), lane));
}

// Wave64 sum via DPP, total broadcast from lane 63. Verified r5..r13.
__device__ __forceinline__ float wred64(float x) {
  int t;
  t = __builtin_amdgcn_update_dpp(0, __float_as_int(x), 0x111, 0xf, 0xf, true); x += __int_as_float(t);
  t = __builtin_amdgcn_update_dpp(0, __float_as_int(x), 0x112, 0xf, 0xf, true); x += __int_as_float(t);
  t = __builtin_amdgcn_update_dpp(0, __float_as_int(x), 0x114, 0xf, 0xf, true); x += __int_as_float(t);
  t = __builtin_amdgcn_update_dpp(0, __float_as_int(x), 0x118, 0xf, 0xf, true); x += __int_as_float(t);
  t = __builtin_amdgcn_update_dpp(0, __float_as_int(x), 0x142, 0xa, 0xf, true); x += __int_as_float(t);
  t = __builtin_amdgcn_update_dpp(0, __float_as_int(x), 0x143, 0xc, 0xf, true); x += __int_as_float(t);
  return rdlane(x, 63);
}

// r13 skeleton (256 WGs, one per (b,half), 6 heads x 2 waves, 2 barriers/iter;
// residency proven). Round-15 changes, both targeting the boundary wave's
// serialized coherence-point round-trips that the barrier convoys behind:
//  1. IMMEDIATE publish: data + vmcnt fence + flag at end of post (r13 deferred
//     the flag a full matvec -> consumer's prefetch always missed).
//  2. DELEGATED cross-read: the boundary head's B-wave (idle during post) does
//     the flag spin + pbuf read and hands off via LDS nbuf/nflag; A overlaps
//     its sigma/coefficient work with that read. Two-phase (flag then data)
//     keeps the producer-fence ordering proof; ring-2 overwrite safety holds
//     because producer seeing flag k implies consumer's A consumed nbuf(k-1).
// S constant-indexed only (r9: runtime index -> scratch spill -> 19.6 GB FETCH).
__global__ __launch_bounds__(768, 1) void mpo_solver(
    const float* __restrict__ mu, const float* __restrict__ L,
    const float* __restrict__ wprev, const float* __restrict__ climit,
    float* __restrict__ out, float* __restrict__ pbuf, int* __restrict__ flags)
{
  const int tid  = threadIdx.x;
  const int lane = tid & 63;
  const int wave = __builtin_amdgcn_readfirstlane(tid >> 6);  // 0..11
  const int j    = wave >> 1;       // local head 0..5
  const int sec  = wave & 1;        // 0 = rows 0-49 + post, 1 = rows 50-99
  const int bid  = blockIdx.x;
  const int b    = bid & 127;
  const int half = bid >> 7;        // 0: heads 0-5, 1: heads 6-11
  const int h    = half * 6 + j;    // global head
  const int bh   = b * 12 + h;

  __shared__ float wbuf[2][6][100];   // double-buffered w per head
  __shared__ float ybuf[6][100];      // y rows 50-99 per head (B-wave's half)
  __shared__ float nbuf[100];         // delegated cross-WG neighbor w (one boundary head/WG)
  __shared__ int   nflag;             // nbuf holds iter-k data -> k

  const float* Lb = L + (size_t)bh * 10000;

  // ---------- Phase 0: SYRK. Lane owns row r of S = L L^T (fp32 regs/AGPRs). ----------
  float S[100];
#pragma unroll
  for (int c = 0; c < 100; ++c) S[c] = 0.f;
  const int r = sec * 50 + lane;      // valid row iff lane < 50
  if (lane < 50) {
#pragma unroll 1
    for (int mc = 0; mc < 25; ++mc) {
      float4 lr = *(const float4*)(Lb + r * 100 + mc * 4);
#pragma unroll
      for (int c = 0; c < 100; ++c) {
        const float* Lc = Lb + c * 100 + mc * 4;   // wave-uniform -> scalar loads
        S[c] = fmaf(lr.x, Lc[0], fmaf(lr.y, Lc[1], fmaf(lr.z, Lc[2], fmaf(lr.w, Lc[3], S[c]))));
      }
    }
  }

  const bool val1 = (lane < 36);
  float mu0 = mu[(size_t)bh * 100 + lane];
  float mu1 = val1 ? mu[(size_t)bh * 100 + 64 + lane] : 0.f;
  float wp0 = wprev[b * 100 + lane];
  float wp1 = val1 ? wprev[b * 100 + 64 + lane] : 0.f;
  float lim = climit[b];

  float w0 = wp0, w1 = wp1;           // post wave's iterate (n = lane, 64+lane)

  if (sec == 0) {
    wbuf[0][j][lane] = wp0;
    if (val1) wbuf[0][j][64 + lane] = wp1;
  }
  if (tid == 0) nflag = 0;
  __syncthreads();

  const bool hasNext = (h < 11);
  const bool isPubL  = (half == 0) && (j == 5);  // boundary head: publishes 5, consumes 6
  const bool isPubH  = (half == 1) && (j == 0);  // boundary head: publishes 6, consumes 5
  const bool isBnd   = isPubL || isPubH;
  const int  flagPub = isPubL ? (b * 2 + 0) : (b * 2 + 1);
  const int  flagCon = isPubL ? (b * 2 + 1) : (b * 2 + 0);
  bool dead = false;
  float thp = -3.0e38f;               // warm Michelot seed; k=0 -> full support

  for (int k = 0; k < NIT; ++k) {
    const int p = k & 1;

    // ---------- matvec y = S * w_k: wave-uniform ds_read_b128 broadcast ----------
    float yloc;
    {
      float a0 = 0.f, a1 = 0.f, a2 = 0.f, a3 = 0.f;
      const float* wrow = wbuf[p][j];
#pragma unroll
      for (int q = 0; q < 25; ++q) {
        float4 wq = *(const float4*)(wrow + q * 4);
        a0 = fmaf(wq.x, S[q * 4 + 0], a0);
        a1 = fmaf(wq.y, S[q * 4 + 1], a1);
        a2 = fmaf(wq.z, S[q * 4 + 2], a2);
        a3 = fmaf(wq.w, S[q * 4 + 3], a3);
      }
      yloc = (a0 + a2) + (a1 + a3);
      if (sec == 1 && lane < 50) ybuf[j][50 + lane] = yloc;  // only B publishes its half
    }
    __syncthreads();

    // ================= post window =================
    if (sec == 1) {
      // ---- B wave of the boundary head: delegated cross-WG read (otherwise idle) ----
      if (isBnd && k > 0) {
        if (!dead) {
          long guard = 0;
          while (flagRead(&flags[flagCon], lane) < k) {
            __builtin_amdgcn_s_sleep(1);
            if (++guard > (1L << 18)) { dead = true; break; }
          }
        }
        // two-phase: data issued only after flag>=k observed (producer fenced
        // data before flag -> flag visible implies data visible)
        float* src = pbuf + ((size_t)flagCon * 2 + (k & 1)) * 100;
        nbuf[lane] = sysLoadF(&src[lane]);
        if (val1) nbuf[64 + lane] = sysLoadF(&src[64 + lane]);
        if (lane == 0) { /* LDS release after LDS writes */ }
        ldsStoreRel(&nflag, k);   // release covers the nbuf LDS writes
      }
    } else {
      // ---------------- A wave: post ----------------
      float y0 = (lane < 50) ? yloc : ybuf[j][lane];
      float y1 = val1 ? ybuf[j][64 + lane] : 0.f;

      float ret = wred64(fmaf(mu0, w0, mu1 * w1));
      float s2  = wred64(fmaf(y0, w0, y1 * w1));
      float sigma = sqrtf(s2 + 1e-12f);
      float z     = KAPPA_ * sigma - ret - lim;
      float act   = (z > 0.f) ? 1.f : 0.f;
      float cY    = 2.f * GAMMA_ + act * (PEN_ * KAPPA_ / sigma);
      float cM    = -(1.f + act * PEN_);

      // neighbor w (iterate k exactly — Jacobi, matches reference)
      float wl0, wl1, wn0 = 0.f, wn1 = 0.f;
      if (j == 0) {
        if (half == 0 || k == 0) { wl0 = wp0; wl1 = wp1; }
        else {
          if (!dead) {
            long guard = 0;
            while (ldsLoadAcq(&nflag) < k) {
              __builtin_amdgcn_s_sleep(1);
              if (++guard > (1L << 18)) { dead = true; break; }
            }
          }
          wl0 = nbuf[lane];
          wl1 = val1 ? nbuf[64 + lane] : 0.f;
        }
      } else { wl0 = wbuf[p][j - 1][lane]; wl1 = val1 ? wbuf[p][j - 1][64 + lane] : 0.f; }
      if (hasNext) {
        if (j == 5) {  // half==0 boundary: next is head 6 (delegated)
          if (k == 0) { wn0 = wp0; wn1 = wp1; }
          else {
            if (!dead) {
              long guard = 0;
              while (ldsLoadAcq(&nflag) < k) {
                __builtin_amdgcn_s_sleep(1);
                if (++guard > (1L << 18)) { dead = true; break; }
              }
            }
            wn0 = nbuf[lane];
            wn1 = val1 ? nbuf[64 + lane] : 0.f;
          }
        } else { wn0 = wbuf[p][j + 1][lane]; wn1 = val1 ? wbuf[p][j + 1][64 + lane] : 0.f; }
      }

      float dw0 = w0 - wl0;
      float g0  = fmaf(cM, mu0, cY * y0) + CC_ * (dw0 * rsqrtf(fmaf(dw0, dw0, 1e-10f)));
      if (hasNext) { float dn0 = wn0 - w0; g0 -= CC_ * (dn0 * rsqrtf(fmaf(dn0, dn0, 1e-10f))); }
      float v0 = fmaf(-LR_, g0, w0);
      float v1 = 0.f;
      if (val1) {
        float dw1 = w1 - wl1;
        float g1  = fmaf(cM, mu1, cY * y1) + CC_ * (dw1 * rsqrtf(fmaf(dw1, dw1, 1e-10f)));
        if (hasNext) { float dn1 = wn1 - w1; g1 -= CC_ * (dn1 * rsqrtf(fmaf(dn1, dn1, 1e-10f))); }
        v1 = fmaf(-LR_, g1, w1);
      }

      // ---- Michelot projection, warm-started (r8/r10/r11/r13-verified numerics) ----
      float a1m = val1 ? 1.f : 0.f;
      float na0 = (v0 > thp) ? 1.f : 0.f;
      float na1 = (val1 && (v1 > thp)) ? 1.f : 0.f;
      float Ssum = wred64(na0 * v0 + na1 * v1);
      float Cnt  = wred64(na0 + na1);
      if (Cnt < 0.5f) { Ssum = wred64(v0 + a1m * v1); Cnt = 100.f; }
      float theta = (Ssum - 1.f) / Cnt;
      for (int it = 0; it < 112; ++it) {
        na0 = (v0 > theta) ? 1.f : 0.f;
        na1 = (val1 && (v1 > theta)) ? 1.f : 0.f;
        float ns = wred64(na0 * v0 + na1 * v1);
        float nc = wred64(na0 + na1);
        if (nc == Cnt && ns == Ssum) break;
        if (it == 7) {  // warm-start may cycle: reset to full support (monotone)
          ns = wred64(v0 + a1m * v1);
          nc = 100.f;
        }
        Ssum = ns; Cnt = nc;
        theta = (Ssum - 1.f) / Cnt;
      }
      thp = theta;
      w0 = fmaxf(v0 - theta, 0.f);
      w1 = val1 ? fmaxf(v1 - theta, 0.f) : 0.f;

      wbuf[1 - p][j][lane] = w0;
      if (val1) wbuf[1 - p][j][64 + lane] = w1;

      // ---- IMMEDIATE cross-WG publish: data, fence, flag (boundary A only) ----
      if (isBnd) {
        float* dst = pbuf + ((size_t)flagPub * 2 + ((k + 1) & 1)) * 100;
        sysStoreF(&dst[lane], w0);
        if (val1) sysStoreF(&dst[64 + lane], w1);
        VMFENCE();   // only this wave's 1-2 stores outstanding -> cheap
        if (lane == 0) sysStoreI(&flags[flagPub], k + 1);
      }
    }
    __syncthreads();
  }

  if (sec == 0) {
    float* o = out + (size_t)bh * 100;
    o[lane] = w0;
    if (val1) o[64 + lane] = w1;
  }
}

extern "C" void kernel_launch(void* const* d_in, const int* in_sizes, int n_in,
                              void* d_out, int out_size, void* d_ws, size_t ws_size,
                              hipStream_t stream) {
  const float* mu = (const float*)d_in[0];
  const float* L  = (const float*)d_in[1];
  const float* wp = (const float*)d_in[2];
  const float* cl = (const float*)d_in[3];
  float* pbuf  = (float*)d_ws;
  int*   flags = (int*)((char*)d_ws + PBUF_BYTES);
  hipMemsetAsync(flags, 0, FLAG_COUNT * sizeof(int), stream);
  hipLaunchKernelGGL(mpo_solver, dim3(256), dim3(768), 0, stream,
                     mu, L, wp, cl, (float*)d_out, pbuf, flags);
}